// Round 13
// baseline (2464.133 us; speedup 1.0000x reference)
//
#include <hip/hip_runtime.h>

// ---------------------------------------------------------------------------
// HeteroGNN (2-layer hetero GAT) forward on MI355X — round 13.
// vs round 12 (passed, 1819us; edge_fused 307us compute-bound with 12
// cross-lane reduce ops/edge): edge kernel rebuilt LANE-PER-EDGE, reduce-free
// (x in VGPRs, Ws uniform-broadcast from LDS, float4-j inner loop, coalesced
// hd writes; self-loop column-means via register cacc[64] + one block fold).
// Also: proj(x_b) deduplicated (computed once; bp's H routed via b1v).
// ---------------------------------------------------------------------------

static constexpr int NPn = 150000;
static constexpr int NBn = 250000;
static constexpr int En  = 500000;

// concatenated CSR layout (256-aligned segments)
static constexpr int OFF_PP = 0;
static constexpr int OFF_BP = 150016;
static constexpr int OFF_BB = 300032;
static constexpr int NCAT   = 550144;
static constexpr int NB_TOT = NCAT / 256;
static constexpr int BS_BP  = OFF_BP / 256;
static constexpr int BS_BB  = OFF_BB / 256;

__device__ __forceinline__ float lrelu(float x, float s) { return x >= 0.0f ? x : s * x; }

__global__ void fill_kernel(float* out, float val, int n) {
  int i = blockIdx.x * blockDim.x + threadIdx.x;
  if (i < n) out[i] = val;
}

// ---------------- batched CSR build ----------------
struct Dsts { const int* d[3]; };

__global__ void zero_int_kernel(int* p, int n) {
  int i = blockIdx.x * blockDim.x + threadIdx.x;
  if (i < n) p[i] = 0;
}

__global__ void hist_all_kernel(Dsts ds, int* __restrict__ cnt) {
  int t = blockIdx.x * blockDim.x + threadIdx.x;
  if (t >= 3 * En) return;
  int rel = t / En, e = t - rel * En;
  int base = (rel == 0) ? OFF_PP : (rel == 1) ? OFF_BP : OFF_BB;
  atomicAdd(&cnt[base + ds.d[rel][e]], 1);
}

__global__ void scan1_kernel(const int* __restrict__ cnt, int* __restrict__ incl,
                             int* __restrict__ bsum, int n) {
  __shared__ int s[256];
  int i = blockIdx.x * 256 + threadIdx.x;
  s[threadIdx.x] = (i < n) ? cnt[i] : 0;
  __syncthreads();
  for (int o = 1; o < 256; o <<= 1) {
    int t = (threadIdx.x >= o) ? s[threadIdx.x - o] : 0;
    __syncthreads();
    s[threadIdx.x] += t;
    __syncthreads();
  }
  if (i < n) incl[i] = s[threadIdx.x];
  if (threadIdx.x == 255) bsum[blockIdx.x] = s[255];
}

__global__ void scan2_kernel(int* bsum) {
  int t = threadIdx.x;
  if (t >= 3) return;
  int lo = (t == 0) ? 0 : (t == 1) ? BS_BP : BS_BB;
  int hi = (t == 0) ? BS_BP : (t == 1) ? BS_BB : NB_TOT;
  int run = 0;
  for (int i = lo; i < hi; ++i) { int v = bsum[i]; bsum[i] = run; run += v; }
}

__global__ void scan3_kernel(const int* __restrict__ cnt, int* __restrict__ offs,
                             const int* __restrict__ bsum, int n) {
  int i = blockIdx.x * 256 + threadIdx.x;
  if (i < n) offs[i] = offs[i] - cnt[i] + bsum[i >> 8];
}

__global__ void copy_int_kernel(const int* __restrict__ src, int* __restrict__ dstp, int n) {
  int i = blockIdx.x * blockDim.x + threadIdx.x;
  if (i < n) dstp[i] = src[i];
}

__global__ void scatter_all_kernel(Dsts ds, int* __restrict__ cursor, int* __restrict__ eidx) {
  int t = blockIdx.x * blockDim.x + threadIdx.x;
  if (t >= 3 * En) return;
  int rel = t / En, e = t - rel * En;
  int base = (rel == 0) ? OFF_PP : (rel == 1) ? OFF_BP : OFF_BB;
  int p = atomicAdd(&cursor[base + ds.d[rel][e]], 1);
  eidx[rel * En + p] = e;
}

// ---------------- dense kernels (proven) ----------------
__global__ void proj_kernel(const float* __restrict__ X, const float* __restrict__ W,
                            const float* __restrict__ b, float* __restrict__ Y, int N) {
  __shared__ __align__(16) float Ws[32 * 64];
  __shared__ float bs[64];
  for (int i = threadIdx.x; i < 32 * 64; i += blockDim.x) Ws[i] = W[i];
  if (threadIdx.x < 64) bs[threadIdx.x] = b[threadIdx.x];
  __syncthreads();
  int row = blockIdx.x * blockDim.x + threadIdx.x;
  if (row >= N) return;
  float x[32];
  const float4* x4 = reinterpret_cast<const float4*>(X + (size_t)row * 32);
#pragma unroll
  for (int k = 0; k < 8; ++k) {
    float4 v = x4[k];
    x[4 * k + 0] = v.x; x[4 * k + 1] = v.y; x[4 * k + 2] = v.z; x[4 * k + 3] = v.w;
  }
  float4* y4 = reinterpret_cast<float4*>(Y + (size_t)row * 64);
#pragma unroll
  for (int cg = 0; cg < 4; ++cg) {
    float acc[16];
#pragma unroll
    for (int c = 0; c < 16; ++c) acc[c] = bs[cg * 16 + c];
#pragma unroll
    for (int k = 0; k < 32; ++k) {
      float xv = x[k];
      const float4* w4 = reinterpret_cast<const float4*>(&Ws[k * 64 + cg * 16]);
#pragma unroll
      for (int q = 0; q < 4; ++q) {
        float4 w = w4[q];
        acc[4 * q + 0] += xv * w.x; acc[4 * q + 1] += xv * w.y;
        acc[4 * q + 2] += xv * w.z; acc[4 * q + 3] += xv * w.w;
      }
    }
#pragma unroll
    for (int q = 0; q < 4; ++q)
      y4[cg * 4 + q] = make_float4(lrelu(acc[4 * q + 0], 0.01f), lrelu(acc[4 * q + 1], 0.01f),
                                   lrelu(acc[4 * q + 2], 0.01f), lrelu(acc[4 * q + 3], 0.01f));
  }
}

// H = X @ W; S1=H.a1; optional S2. X/H may alias (row-private).
__global__ void hgemm_kernel(const float* X, const float* __restrict__ W,
                             const float* __restrict__ a1, const float* __restrict__ a2,
                             float* H, float* __restrict__ S1,
                             float* __restrict__ S2, int N) {
  __shared__ __align__(16) float Ws[64 * 64];
  __shared__ float a1s[64], a2s[64];
  for (int i = threadIdx.x; i < 64 * 64; i += blockDim.x) Ws[i] = W[i];
  if (threadIdx.x < 64) {
    a1s[threadIdx.x] = a1[threadIdx.x];
    a2s[threadIdx.x] = a2 ? a2[threadIdx.x] : 0.0f;
  }
  __syncthreads();
  int row = blockIdx.x * blockDim.x + threadIdx.x;
  if (row >= N) return;
  float x[64];
  const float4* x4 = reinterpret_cast<const float4*>(X + (size_t)row * 64);
#pragma unroll
  for (int k = 0; k < 16; ++k) {
    float4 v = x4[k];
    x[4 * k + 0] = v.x; x[4 * k + 1] = v.y; x[4 * k + 2] = v.z; x[4 * k + 3] = v.w;
  }
  float4* h4 = reinterpret_cast<float4*>(H + (size_t)row * 64);
  float s1 = 0.0f, s2 = 0.0f;
#pragma unroll
  for (int cg = 0; cg < 4; ++cg) {
    float acc[16];
#pragma unroll
    for (int c = 0; c < 16; ++c) acc[c] = 0.0f;
#pragma unroll
    for (int k = 0; k < 64; ++k) {
      float xv = x[k];
      const float4* w4 = reinterpret_cast<const float4*>(&Ws[k * 64 + cg * 16]);
#pragma unroll
      for (int q = 0; q < 4; ++q) {
        float4 w = w4[q];
        acc[4 * q + 0] += xv * w.x; acc[4 * q + 1] += xv * w.y;
        acc[4 * q + 2] += xv * w.z; acc[4 * q + 3] += xv * w.w;
      }
    }
#pragma unroll
    for (int c = 0; c < 16; ++c) {
      s1 += acc[c] * a1s[cg * 16 + c];
      s2 += acc[c] * a2s[cg * 16 + c];
    }
#pragma unroll
    for (int q = 0; q < 4; ++q)
      h4[cg * 4 + q] = make_float4(acc[4 * q + 0], acc[4 * q + 1], acc[4 * q + 2], acc[4 * q + 3]);
  }
  S1[row] = s1;
  if (S2) S2[row] = s2;
}

__global__ void matvec_kernel(const float* __restrict__ X, const float* __restrict__ v,
                              float* __restrict__ out, int N) {
  __shared__ float vs[64];
  if (threadIdx.x < 64) vs[threadIdx.x] = v[threadIdx.x];
  __syncthreads();
  int i = blockIdx.x * blockDim.x + threadIdx.x;
  if (i >= N) return;
  const float4* x4 = reinterpret_cast<const float4*>(X + (size_t)i * 64);
  float s = 0.0f;
#pragma unroll
  for (int k = 0; k < 16; ++k) {
    float4 u = x4[k];
    s += u.x * vs[4 * k + 0] + u.y * vs[4 * k + 1] + u.z * vs[4 * k + 2] + u.w * vs[4 * k + 3];
  }
  out[i] = s;
}

__global__ void head_kernel(const float* __restrict__ X, const float* __restrict__ w,
                            const float* __restrict__ b, float* __restrict__ out, int N) {
  __shared__ float vs[64];
  if (threadIdx.x < 64) vs[threadIdx.x] = w[threadIdx.x];
  __syncthreads();
  int i = blockIdx.x * blockDim.x + threadIdx.x;
  if (i >= N) return;
  const float4* x4 = reinterpret_cast<const float4*>(X + (size_t)i * 64);
  float s = b[0];
#pragma unroll
  for (int k = 0; k < 16; ++k) {
    float4 u = x4[k];
    s += u.x * vs[4 * k + 0] + u.y * vs[4 * k + 1] + u.z * vs[4 * k + 2] + u.w * vs[4 * k + 3];
  }
  out[i] = s;
}

struct RowdotJobs { const float* M[7]; const float* v[7]; float* out[7]; };
__global__ void rowdot_batch_kernel(RowdotJobs J) {
  __shared__ float vs[64];
  int j = blockIdx.x;
  vs[threadIdx.x] = J.v[j][threadIdx.x];
  __syncthreads();
  float s = 0.0f;
  const float* M = J.M[j];
#pragma unroll
  for (int c = 0; c < 64; ++c) s += M[threadIdx.x * 64 + c] * vs[c];
  J.out[j][threadIdx.x] = s;
}

// ---------------- lane-per-edge fused edge kernel ----------------
// Per edge (one thread): hd1 = lrelu(ea@We+be)·wa1 (hd2 with wa2); x in VGPRs,
// Ws uniform-broadcast from LDS (float4 over j-groups), coalesced hd writes.
// Column sums of lrelu(...) for the self-loop mean kept in cacc[64] registers
// and folded per block (rel 0 -> sum_pp, rel 1 -> sum_bb).
struct EdgeJobs {
  const float* EA[3]; const float* We[3]; const float* be[3];
  const float* wa1[3]; const float* wa2[3]; float* hd1[3]; float* hd2[3];
};
__global__ void edge_fused_kernel(EdgeJobs J, float* __restrict__ sum_pp,
                                  float* __restrict__ sum_bb) {
  int rel = blockIdx.x >> 9;          // 512 blocks per relation
  int blk = blockIdx.x & 511;
  __shared__ __align__(16) float Ws[16 * 64];
  __shared__ __align__(16) float bs[64], w1s[64], w2s[64];
  __shared__ float lsum[4 * 64];
  const float* We = J.We[rel];
  for (int i = threadIdx.x; i < 16 * 64; i += blockDim.x) Ws[i] = We[i];
  bool has2 = (J.wa2[rel] != nullptr);
  bool needm = (rel < 2);
  if (threadIdx.x < 64) {
    bs[threadIdx.x] = J.be[rel][threadIdx.x];
    w1s[threadIdx.x] = J.wa1[rel][threadIdx.x];
    w2s[threadIdx.x] = has2 ? J.wa2[rel][threadIdx.x] : 0.0f;
  }
  __syncthreads();
  const float4* Ws4 = reinterpret_cast<const float4*>(Ws);
  const float4* bs4 = reinterpret_cast<const float4*>(bs);
  const float4* w1s4 = reinterpret_cast<const float4*>(w1s);
  const float4* w2s4 = reinterpret_cast<const float4*>(w2s);
  const float* EA = J.EA[rel];
  float* hd1 = J.hd1[rel];
  float* hd2 = J.hd2[rel];
  float cacc[64];
#pragma unroll
  for (int c = 0; c < 64; ++c) cacc[c] = 0.0f;
  for (int e = blk * 256 + threadIdx.x; e < En; e += 512 * 256) {
    float x[16];
    const float4* xa = reinterpret_cast<const float4*>(EA + (size_t)e * 16);
#pragma unroll
    for (int k = 0; k < 4; ++k) {
      float4 v = xa[k];
      x[4 * k + 0] = v.x; x[4 * k + 1] = v.y; x[4 * k + 2] = v.z; x[4 * k + 3] = v.w;
    }
    float d1 = 0.0f, d2 = 0.0f;
#pragma unroll
    for (int jg = 0; jg < 16; ++jg) {
      float4 t = bs4[jg];
#pragma unroll
      for (int k = 0; k < 16; ++k) {
        float4 w = Ws4[k * 16 + jg];   // uniform across lanes -> broadcast
        t.x += x[k] * w.x; t.y += x[k] * w.y; t.z += x[k] * w.z; t.w += x[k] * w.w;
      }
      t.x = lrelu(t.x, 0.01f); t.y = lrelu(t.y, 0.01f);
      t.z = lrelu(t.z, 0.01f); t.w = lrelu(t.w, 0.01f);
      if (needm) {
        cacc[jg * 4 + 0] += t.x; cacc[jg * 4 + 1] += t.y;
        cacc[jg * 4 + 2] += t.z; cacc[jg * 4 + 3] += t.w;
      }
      float4 w1 = w1s4[jg];
      d1 += t.x * w1.x + t.y * w1.y + t.z * w1.z + t.w * w1.w;
      float4 w2 = w2s4[jg];
      d2 += t.x * w2.x + t.y * w2.y + t.z * w2.z + t.w * w2.w;
    }
    hd1[e] = d1;
    if (has2) hd2[e] = d2;
  }
  if (needm) {
    int lane = threadIdx.x & 63, wid = threadIdx.x >> 6;
#pragma unroll
    for (int j = 0; j < 64; ++j) {
      float v = cacc[j];
#pragma unroll
      for (int o = 32; o >= 1; o >>= 1) v += __shfl_xor(v, o, 64);
      if (lane == 0) lsum[wid * 64 + j] = v;
    }
    __syncthreads();
    if (threadIdx.x < 64) {
      float s = lsum[threadIdx.x] + lsum[64 + threadIdx.x] +
                lsum[128 + threadIdx.x] + lsum[192 + threadIdx.x];
      atomicAdd(rel == 0 ? &sum_pp[threadIdx.x] : &sum_bb[threadIdx.x], s);
    }
  }
}

struct SelfJobs { const float* sum[3]; const float* wa[3]; float* out[3]; };
__global__ void selfdot_batch_kernel(SelfJobs J, float invE) {
  int job = threadIdx.x >> 6, lane = threadIdx.x & 63;
  float v = J.sum[job][lane] * J.wa[job][lane] * invE;
#pragma unroll
  for (int o = 32; o >= 1; o >>= 1) v += __shfl_down(v, o, 64);
  if (lane == 0) J.out[job][0] = v;
}

// ---------------- single-pass fused per-row GAT ----------------
__global__ void gat_row_kernel(const int* __restrict__ offs, const int* __restrict__ eidx,
                               const int* __restrict__ esrc,
                               const float* __restrict__ ssrc, const float* __restrict__ sdst,
                               const float* __restrict__ hd, const float* __restrict__ selfhd,
                               const float* __restrict__ H, const float* __restrict__ bias,
                               float* __restrict__ out, int N, int accum) {
  int wid = (int)(((size_t)blockIdx.x * blockDim.x + threadIdx.x) >> 6);
  int lane = threadIdx.x & 63;
  if (wid >= N) return;
  int lo = offs[wid], hi = offs[wid + 1];
  float sd = sdst[wid];
  float wsum = 1e-16f;
  float acc = 0.0f;
  if (selfhd) {
    float wself = __expf(lrelu(ssrc[wid] + sd + selfhd[0], 0.2f));
    wsum += wself;
    acc = wself * H[(size_t)wid * 64 + lane];
  }
  for (int p = lo; p < hi; ++p) {
    int e = eidx[p];
    int s = esrc[e];
    float w = __expf(lrelu(ssrc[s] + sd + hd[e], 0.2f));
    wsum += w;
    acc += w * H[(size_t)s * 64 + lane];
  }
  float r = acc / wsum + bias[lane];
  size_t o = (size_t)wid * 64 + lane;
  if (accum) out[o] += r;
  else       out[o] = r;
}

extern "C" void kernel_launch(void* const* d_in, const int* in_sizes, int n_in,
                              void* d_out, int out_size, void* d_ws, size_t ws_size,
                              hipStream_t stream) {
  dim3 B(256);
  auto cdiv = [](int a, int b) { return (a + b - 1) / b; };

  bool okmap = (n_in == 58) &&
               in_sizes[0] == NPn * 32 && in_sizes[1] == NBn * 32 &&
               in_sizes[2] == En * 16 && in_sizes[15] == 4096 &&
               in_sizes[17] == 64 && in_sizes[53] == 64 &&
               in_sizes[55] == 2 * En && in_sizes[57] == 2 * En;
  if (!okmap) {
    fill_kernel<<<cdiv(NPn, 256), B, 0, stream>>>((float*)d_out, 1000.0f, NPn);
    return;
  }

  const float* x_p  = (const float*)d_in[0];
  const float* x_b  = (const float*)d_in[1];
  const float* ea_pp = (const float*)d_in[2];
  const float* ea_bb = (const float*)d_in[3];
  const float* ea_bp = (const float*)d_in[4];
  const float* W_node_p = (const float*)d_in[5];
  const float* b_node_p = (const float*)d_in[6];
  const float* W_node_b = (const float*)d_in[7];
  const float* b_node_b = (const float*)d_in[8];
  const float* W_edge_pp = (const float*)d_in[9];
  const float* b_edge_pp = (const float*)d_in[10];
  const float* W_edge_bb = (const float*)d_in[11];
  const float* b_edge_bb = (const float*)d_in[12];
  const float* W_edge_bp = (const float*)d_in[13];
  const float* b_edge_bp = (const float*)d_in[14];
  const float* c1_pp_W = (const float*)d_in[15];
  const float* c1_pp_We = (const float*)d_in[16];
  const float* c1_pp_asrc = (const float*)d_in[17];
  const float* c1_pp_adst = (const float*)d_in[18];
  const float* c1_pp_aedge = (const float*)d_in[19];
  const float* c1_pp_bias = (const float*)d_in[20];
  const float* c1_bb_W = (const float*)d_in[21];
  const float* c1_bb_We = (const float*)d_in[22];
  const float* c1_bb_asrc = (const float*)d_in[23];
  const float* c1_bb_adst = (const float*)d_in[24];
  const float* c1_bb_aedge = (const float*)d_in[25];
  const float* c1_bb_bias = (const float*)d_in[26];
  const float* c1_bp_Wsrc = (const float*)d_in[27];
  const float* c1_bp_Wdst = (const float*)d_in[28];
  const float* c1_bp_We = (const float*)d_in[29];
  const float* c1_bp_asrc = (const float*)d_in[30];
  const float* c1_bp_adst = (const float*)d_in[31];
  const float* c1_bp_aedge = (const float*)d_in[32];
  const float* c1_bp_bias = (const float*)d_in[33];
  const float* c2_pp_W = (const float*)d_in[34];
  const float* c2_pp_We = (const float*)d_in[35];
  const float* c2_pp_asrc = (const float*)d_in[36];
  const float* c2_pp_adst = (const float*)d_in[37];
  const float* c2_pp_aedge = (const float*)d_in[38];
  const float* c2_pp_bias = (const float*)d_in[39];
  const float* c2_bp_Wsrc = (const float*)d_in[46];
  const float* c2_bp_Wdst = (const float*)d_in[47];
  const float* c2_bp_We = (const float*)d_in[48];
  const float* c2_bp_asrc = (const float*)d_in[49];
  const float* c2_bp_adst = (const float*)d_in[50];
  const float* c2_bp_aedge = (const float*)d_in[51];
  const float* c2_bp_bias = (const float*)d_in[52];
  const float* W_out = (const float*)d_in[53];
  const float* b_out = (const float*)d_in[54];
  const int* ei_pp = (const int*)d_in[55];
  const int* ei_bb = (const int*)d_in[56];
  const int* ei_bp = (const int*)d_in[57];

  // ---- workspace layout
  float* ws = (float*)d_ws;
  int* offs_cat = (int*)ws;                  // NCAT
  int* cnt_cat  = offs_cat + NCAT;           // NCAT
  int* bsum     = cnt_cat + NCAT;            // pad 2560
  int* eidx_cat = bsum + 2560;               // 3*En
  float* xp    = (float*)(eidx_cat + 3 * En);// NPn*64 (p2 aliases)
  float* p1    = xp + (size_t)NPn * 64;      // NPn*64
  float* b1v   = p1 + (size_t)NPn * 64;      // NBn*64
  float* hbuf  = b1v + (size_t)NBn * 64;     // NBn*64
  float* hd_pp1 = hbuf + (size_t)NBn * 64;   // En x5
  float* hd_pp2 = hd_pp1 + En;
  float* hd_bb1 = hd_pp2 + En;
  float* hd_bp1 = hd_bb1 + En;
  float* hd_bp2 = hd_bp1 + En;
  float* s_src = hd_bp2 + En;                // NBn
  float* s_dst = s_src + NBn;                // NBn
  float* small = s_dst + NBn;                // 1024
  float* p2    = xp;

  const size_t NEED = (size_t)(small + 1024 - ws) * sizeof(float);
  if (ws_size < NEED) {
    fill_kernel<<<cdiv(NPn, 256), B, 0, stream>>>((float*)d_out, 500.0f, NPn);
    return;
  }

  float* sum_pp  = small + 0;   float* sum_bb  = small + 64;
  float* wa_pp1  = small + 128; float* wa_pp2  = small + 192;
  float* wa_bb1  = small + 256; float* wa_bp1  = small + 320; float* wa_bp2 = small + 384;
  float* wd1     = small + 448; float* wd2     = small + 512;
  float* self_pp1= small + 576; float* self_pp2= small + 577; float* self_bb1 = small + 578;
  const float invE = 1.0f / (float)En;

  hipMemsetAsync(sum_pp, 0, 128 * sizeof(float), stream);

  // ---- projections, collapsed vectors, edge scalars
  proj_kernel<<<cdiv(NPn, 256), B, 0, stream>>>(x_p, W_node_p, b_node_p, xp, NPn);

  RowdotJobs RJ;
  RJ.M[0] = c1_pp_We;  RJ.v[0] = c1_pp_aedge; RJ.out[0] = wa_pp1;
  RJ.M[1] = c2_pp_We;  RJ.v[1] = c2_pp_aedge; RJ.out[1] = wa_pp2;
  RJ.M[2] = c1_bb_We;  RJ.v[2] = c1_bb_aedge; RJ.out[2] = wa_bb1;
  RJ.M[3] = c1_bp_We;  RJ.v[3] = c1_bp_aedge; RJ.out[3] = wa_bp1;
  RJ.M[4] = c2_bp_We;  RJ.v[4] = c2_bp_aedge; RJ.out[4] = wa_bp2;
  RJ.M[5] = c1_bp_Wdst; RJ.v[5] = c1_bp_adst; RJ.out[5] = wd1;
  RJ.M[6] = c2_bp_Wdst; RJ.v[6] = c2_bp_adst; RJ.out[6] = wd2;
  rowdot_batch_kernel<<<7, 64, 0, stream>>>(RJ);

  EdgeJobs EJ;
  EJ.EA[0] = ea_pp; EJ.We[0] = W_edge_pp; EJ.be[0] = b_edge_pp;
  EJ.wa1[0] = wa_pp1; EJ.wa2[0] = wa_pp2; EJ.hd1[0] = hd_pp1; EJ.hd2[0] = hd_pp2;
  EJ.EA[1] = ea_bb; EJ.We[1] = W_edge_bb; EJ.be[1] = b_edge_bb;
  EJ.wa1[1] = wa_bb1; EJ.wa2[1] = nullptr; EJ.hd1[1] = hd_bb1; EJ.hd2[1] = nullptr;
  EJ.EA[2] = ea_bp; EJ.We[2] = W_edge_bp; EJ.be[2] = b_edge_bp;
  EJ.wa1[2] = wa_bp1; EJ.wa2[2] = wa_bp2; EJ.hd1[2] = hd_bp1; EJ.hd2[2] = hd_bp2;
  edge_fused_kernel<<<3 * 512, B, 0, stream>>>(EJ, sum_pp, sum_bb);

  SelfJobs SJ;
  SJ.sum[0] = sum_pp; SJ.wa[0] = wa_pp1; SJ.out[0] = self_pp1;
  SJ.sum[1] = sum_pp; SJ.wa[1] = wa_pp2; SJ.out[1] = self_pp2;
  SJ.sum[2] = sum_bb; SJ.wa[2] = wa_bb1; SJ.out[2] = self_bb1;
  selfdot_batch_kernel<<<1, 192, 0, stream>>>(SJ, invE);

  // ---- batched CSR build
  Dsts DS; DS.d[0] = ei_pp + En; DS.d[1] = ei_bp + En; DS.d[2] = ei_bb + En;
  zero_int_kernel<<<cdiv(NCAT, 256), B, 0, stream>>>(cnt_cat, NCAT);
  hist_all_kernel<<<cdiv(3 * En, 256), B, 0, stream>>>(DS, cnt_cat);
  scan1_kernel<<<NB_TOT, B, 0, stream>>>(cnt_cat, offs_cat, bsum, NCAT);
  scan2_kernel<<<1, 64, 0, stream>>>(bsum);
  scan3_kernel<<<NB_TOT, B, 0, stream>>>(cnt_cat, offs_cat, bsum, NCAT);
  copy_int_kernel<<<cdiv(NCAT, 256), B, 0, stream>>>(offs_cat, cnt_cat, NCAT);
  scatter_all_kernel<<<cdiv(3 * En, 256), B, 0, stream>>>(DS, cnt_cat, eidx_cat);

  const int* offs_pp = offs_cat + OFF_PP;
  const int* offs_bp = offs_cat + OFF_BP;
  const int* offs_bb = offs_cat + OFF_BB;
  const int* eidx_pp = eidx_cat;
  const int* eidx_bp = eidx_cat + En;
  const int* eidx_bb = eidx_cat + 2 * En;

  // ---- conv1 pp (homo) -> p1
  hgemm_kernel<<<cdiv(NPn, 256), B, 0, stream>>>(xp, c1_pp_W, c1_pp_asrc, c1_pp_adst, hbuf, s_src, s_dst, NPn);
  gat_row_kernel<<<cdiv(NPn * 64, 256), B, 0, stream>>>(offs_pp, eidx_pp, ei_pp, s_src, s_dst,
      hd_pp1, self_pp1, hbuf, c1_pp_bias, p1, NPn, 0);

  // ---- xb computed ONCE -> hbuf; conv1-bp H via b1v; conv1-bb in-place
  proj_kernel<<<cdiv(NBn, 256), B, 0, stream>>>(x_b, W_node_b, b_node_b, hbuf, NBn);

  // conv1 bp (b->p) -> p1 (+=), H in b1v
  hgemm_kernel<<<cdiv(NBn, 256), B, 0, stream>>>(hbuf, c1_bp_Wsrc, c1_bp_asrc, nullptr, b1v, s_src, nullptr, NBn);
  matvec_kernel<<<cdiv(NPn, 256), B, 0, stream>>>(xp, wd1, s_dst, NPn);
  gat_row_kernel<<<cdiv(NPn * 64, 256), B, 0, stream>>>(offs_bp, eidx_bp, ei_bp, s_src, s_dst,
      hd_bp1, nullptr, b1v, c1_bp_bias, p1, NPn, 1);

  // conv1 bb (homo) -> b1v (gat_row output overwrites b1v after bp consumed it)
  hgemm_kernel<<<cdiv(NBn, 256), B, 0, stream>>>(hbuf, c1_bb_W, c1_bb_asrc, c1_bb_adst, hbuf, s_src, s_dst, NBn);
  gat_row_kernel<<<cdiv(NBn * 64, 256), B, 0, stream>>>(offs_bb, eidx_bb, ei_bb, s_src, s_dst,
      hd_bb1, self_bb1, hbuf, c1_bb_bias, b1v, NBn, 0);

  // ---- conv2 pp (homo, input p1) -> p2
  hgemm_kernel<<<cdiv(NPn, 256), B, 0, stream>>>(p1, c2_pp_W, c2_pp_asrc, c2_pp_adst, hbuf, s_src, s_dst, NPn);
  gat_row_kernel<<<cdiv(NPn * 64, 256), B, 0, stream>>>(offs_pp, eidx_pp, ei_pp, s_src, s_dst,
      hd_pp2, self_pp2, hbuf, c2_pp_bias, p2, NPn, 0);

  // ---- conv2 bp (src b1v) -> p2 (+=)
  hgemm_kernel<<<cdiv(NBn, 256), B, 0, stream>>>(b1v, c2_bp_Wsrc, c2_bp_asrc, nullptr, hbuf, s_src, nullptr, NBn);
  matvec_kernel<<<cdiv(NPn, 256), B, 0, stream>>>(p1, wd2, s_dst, NPn);
  gat_row_kernel<<<cdiv(NPn * 64, 256), B, 0, stream>>>(offs_bp, eidx_bp, ei_bp, s_src, s_dst,
      hd_bp2, nullptr, hbuf, c2_bp_bias, p2, NPn, 1);

  // ---- head
  head_kernel<<<cdiv(NPn, 256), B, 0, stream>>>(p2, W_out, b_out, (float*)d_out, NPn);
}